// Round 2
// baseline (508.078 us; speedup 1.0000x reference)
//
#include <hip/hip_runtime.h>

// Problem constants (B,S,D,H,HD) = (4,1024,1024,16,64)
#define B_ 4
#define S_ 1024
#define D_ 1024
#define H_ 16
#define E_ 64
#define BS_ (B_*S_)

typedef __attribute__((ext_vector_type(8))) short bf16x8;   // 8 bf16 in 4 VGPRs
typedef __attribute__((ext_vector_type(4))) float f32x4;

__device__ __forceinline__ unsigned short f2bf(float f) {
    unsigned int x = __float_as_uint(f);
    x = (x + 0x7FFFu + ((x >> 16) & 1u)) >> 16;   // RNE
    return (unsigned short)x;
}
__device__ __forceinline__ float bf2f(unsigned short u) {
    return __uint_as_float(((unsigned int)u) << 16);
}
// read input element i as float, dtype per runtime flag (1=bf16, 0=fp32)
__device__ __forceinline__ float ldin(const void* p, size_t i, int isb) {
    return isb ? bf2f(((const unsigned short*)p)[i]) : ((const float*)p)[i];
}

// ---------------------------------------------------------------------------
// Kernel 0: detect input dtype. bf16 data: low 16 bits of each dword are a
// bf16 of N(0,1) -> exponent field in [100,145] ~always. fp32 data: low 16
// bits are uniform mantissa bits -> ~18% in-window. 256 samples separate
// cleanly (256 vs ~46 expected hits).
// ---------------------------------------------------------------------------
__global__ void detect_dtype(const unsigned int* q, int* flag) {
    __shared__ int cnt;
    if (threadIdx.x == 0) cnt = 0;
    __syncthreads();
    unsigned int w = q[threadIdx.x];
    unsigned int lo = w & 0xFFFFu;
    unsigned int e = (lo >> 7) & 0xFFu;
    int ok = (lo == 0u) || (e >= 100u && e <= 145u);
    atomicAdd(&cnt, ok);
    __syncthreads();
    if (threadIdx.x == 0) flag[0] = (cnt >= 240) ? 1 : 0;
}

// ---------------------------------------------------------------------------
// Kernel 1: weight permutes (to B^T layouts for MFMA B-operand) + biases.
//   WqT[(h*64+e)][d] = Wq[h][d][e]   (same for Wk, Wv)
//   WoT[o][d]        = Wo[d][o]
// grid = 4096 blocks x 256 threads => i in [0, 1M)
// ---------------------------------------------------------------------------
__global__ void conv_w(const void* Wq, const void* Wk, const void* Wv, const void* Wo,
                       const void* bq_, const void* bk_, const void* bv_, const void* bo_,
                       unsigned short* WqT, unsigned short* WkT, unsigned short* WvT,
                       unsigned short* WoT,
                       float* bq, float* bk, float* bv, float* bo, const int* flag) {
    int isb = flag[0];
    int i = blockIdx.x * 256 + threadIdx.x;     // 0..1M-1
    {
        int h = i >> 16;             // i / (D*E)
        int rem = i & 65535;
        int d = rem >> 6, e = rem & 63;
        size_t dsti = (size_t)((h << 6) + e) * D_ + d;
        WqT[dsti] = f2bf(ldin(Wq, i, isb));
        WkT[dsti] = f2bf(ldin(Wk, i, isb));
        WvT[dsti] = f2bf(ldin(Wv, i, isb));
    }
    {
        int d = i >> 10, o = i & 1023;
        WoT[(size_t)o * D_ + d] = f2bf(ldin(Wo, i, isb));
    }
    if (i < 1024) {
        bq[i] = ldin(bq_, i, isb);
        bk[i] = ldin(bk_, i, isb);
        bv[i] = ldin(bv_, i, isb);
        bo[i] = ldin(bo_, i, isb);
    }
}

// ---------------------------------------------------------------------------
// Kernel 2: bf16 MFMA GEMM, C[M][N] = A[M][K] * Bt[N][K]^T + bias[N]
// M=4096, N=1024, K=1024. 128x128 tile/block, 4 waves in 2x2, each wave 64x64
// (4x4 of 16x16x32 MFMA). Single-buffered LDS staging, +8 ushort row pad.
// amode: 0 = A is raw input (dtype per flag), 1 = A is bf16 (heads buffer)
// outmode: 0 = write bf16 [B,H,S,E] (projections), 1 = write d_out per flag
// ---------------------------------------------------------------------------
#define LSTR 40   // LDS row stride in ushorts (32 + 8 pad -> 80B rows)

__global__ __launch_bounds__(256) void gemm128(
        const void* A, const unsigned short* Bt, const float* bias,
        void* dst, int outmode, int amode, const int* flag) {
    __shared__ unsigned short As[128 * LSTR];
    __shared__ unsigned short Bs[128 * LSTR];

    const int fl = flag[0];
    const int aisb = (amode == 1) ? 1 : fl;
    const int m0 = blockIdx.y * 128, n0 = blockIdx.x * 128;
    const int t = threadIdx.x;
    const int lane = t & 63, lm = lane & 15, q4 = lane >> 4;
    const int w = t >> 6, wm = w >> 1, wn = w & 1;

    f32x4 acc[4][4];
#pragma unroll
    for (int i = 0; i < 4; i++)
#pragma unroll
        for (int j = 0; j < 4; j++) acc[i][j] = (f32x4){0.f, 0.f, 0.f, 0.f};

    for (int kk = 0; kk < D_; kk += 32) {
        __syncthreads();
        // stage A (with dtype conversion) and Bt: 128 rows x 32 cols each
#pragma unroll
        for (int rc = 0; rc < 2; ++rc) {
            int c = t + rc * 256;            // 0..511
            int row = c >> 2, cc = c & 3;    // row 0..127, 16B chunk 0..3
            size_t gidx = (size_t)(m0 + row) * D_ + kk + cc * 8;
            if (aisb) {
                *(bf16x8*)&As[row * LSTR + cc * 8] =
                    *(const bf16x8*)((const unsigned short*)A + gidx);
            } else {
                const float* af = (const float*)A + gidx;
                bf16x8 v;
#pragma unroll
                for (int j = 0; j < 8; j++) v[j] = (short)f2bf(af[j]);
                *(bf16x8*)&As[row * LSTR + cc * 8] = v;
            }
            *(bf16x8*)&Bs[row * LSTR + cc * 8] =
                *(const bf16x8*)&Bt[(size_t)(n0 + row) * D_ + kk + cc * 8];
        }
        __syncthreads();

        bf16x8 af[4], bf[4];
#pragma unroll
        for (int mt = 0; mt < 4; mt++)
            af[mt] = *(const bf16x8*)&As[(wm * 64 + mt * 16 + lm) * LSTR + q4 * 8];
#pragma unroll
        for (int nt = 0; nt < 4; nt++)
            bf[nt] = *(const bf16x8*)&Bs[(wn * 64 + nt * 16 + lm) * LSTR + q4 * 8];
#pragma unroll
        for (int mt = 0; mt < 4; mt++)
#pragma unroll
            for (int nt = 0; nt < 4; nt++)
                acc[mt][nt] = __builtin_amdgcn_mfma_f32_16x16x32_bf16(
                    af[mt], bf[nt], acc[mt][nt], 0, 0, 0);
    }

    // epilogue: C/D layout col=lane&15, row=(lane>>4)*4+reg
#pragma unroll
    for (int mt = 0; mt < 4; mt++)
#pragma unroll
        for (int nt = 0; nt < 4; nt++)
#pragma unroll
            for (int r = 0; r < 4; r++) {
                int M = m0 + wm * 64 + mt * 16 + q4 * 4 + r;
                int N = n0 + wn * 64 + nt * 16 + lm;
                float v = acc[mt][nt][r] + bias[N];
                if (outmode == 0) {
                    int bb = M >> 10, s = M & 1023, hh = N >> 6, e = N & 63;
                    ((unsigned short*)dst)[((size_t)(bb * H_ + hh) * S_ + s) * E_ + e] = f2bf(v);
                } else {
                    size_t idx = (size_t)M * D_ + N;
                    if (fl) ((unsigned short*)dst)[idx] = f2bf(v);
                    else    ((float*)dst)[idx] = v;
                }
            }
}

// ---------------------------------------------------------------------------
// Kernel 3: fused attention. Block = (b, h, 64 Q rows), 4 waves, wave = 16 Q
// rows. Loop over 16 K-tiles of 64 keys: QK^T via MFMA (K frags direct from
// global, contiguous 16B), scale 1/sqrt(1024), mask->-3e38 (underflow => exact
// parity with ref's +NEG then *m), online softmax, P through LDS (C-layout ->
// A-layout), V tile transposed in LDS, PV via MFMA. Normalize by l at end.
// ---------------------------------------------------------------------------
__global__ __launch_bounds__(256) void attn64(
        const unsigned short* Qp, const unsigned short* Kp, const unsigned short* Vp,
        const int* mask, unsigned short* heads) {
    __shared__ unsigned short Vt[64 * 80];      // Vt[e][k], stride 80
    __shared__ unsigned short Pw[4][16 * 80];   // per-wave P[row][k], stride 80

    const int qt = blockIdx.x, h = blockIdx.y, b = blockIdx.z;
    const int t = threadIdx.x, w = t >> 6, lane = t & 63, lm = lane & 15, q4 = lane >> 4;
    const size_t bh = ((size_t)b * H_ + h) * S_ * E_;
    const unsigned short* Qb = Qp + bh;
    const unsigned short* Kb = Kp + bh;
    const unsigned short* Vb = Vp + bh;
    const int* mb = mask + (size_t)b * S_ * S_;
    const int qr0 = qt * 64 + w * 16;

    // Q A-fragments, held in registers for the whole K loop
    bf16x8 aq0 = *(const bf16x8*)&Qb[(size_t)(qr0 + lm) * E_ + q4 * 8];
    bf16x8 aq1 = *(const bf16x8*)&Qb[(size_t)(qr0 + lm) * E_ + 32 + q4 * 8];

    f32x4 oacc[4];
    float mrun[4], lrun[4];
#pragma unroll
    for (int i = 0; i < 4; i++) {
        oacc[i] = (f32x4){0.f, 0.f, 0.f, 0.f};
        mrun[i] = -3.0e38f;
        lrun[i] = 0.f;
    }
    const float scale = 0.03125f;   // 1/sqrt(D=1024) -- ref uses full D, not HD

    for (int kt = 0; kt < S_ / 64; ++kt) {
        const int k0 = kt * 64;
        // scores: 16 q-rows x 64 keys per wave
        f32x4 sc[4];
#pragma unroll
        for (int nt = 0; nt < 4; ++nt) {
            bf16x8 b0 = *(const bf16x8*)&Kb[(size_t)(k0 + nt * 16 + lm) * E_ + q4 * 8];
            bf16x8 b1 = *(const bf16x8*)&Kb[(size_t)(k0 + nt * 16 + lm) * E_ + 32 + q4 * 8];
            f32x4 z = (f32x4){0.f, 0.f, 0.f, 0.f};
            z = __builtin_amdgcn_mfma_f32_16x16x32_bf16(aq0, b0, z, 0, 0, 0);
            z = __builtin_amdgcn_mfma_f32_16x16x32_bf16(aq1, b1, z, 0, 0, 0);
            sc[nt] = z;
        }
        // mask + scale
        float sv[4][4];
#pragma unroll
        for (int nt = 0; nt < 4; ++nt)
#pragma unroll
            for (int r = 0; r < 4; r++) {
                int mv = mb[(size_t)(qr0 + q4 * 4 + r) * S_ + k0 + nt * 16 + lm];
                sv[nt][r] = mv ? sc[nt][r] * scale : -3.0e38f;
            }
        // online softmax update (row reductions across the 16-lane group)
        float alpha[4];
        unsigned short pb[4][4];
#pragma unroll
        for (int r = 0; r < 4; r++) {
            float tmx = fmaxf(fmaxf(sv[0][r], sv[1][r]), fmaxf(sv[2][r], sv[3][r]));
#pragma unroll
            for (int off = 1; off < 16; off <<= 1) tmx = fmaxf(tmx, __shfl_xor(tmx, off, 64));
            float mnew = fmaxf(mrun[r], tmx);
            alpha[r] = __expf(mrun[r] - mnew);    // all-masked-so-far rows self-correct later
            float s_ = 0.f;
#pragma unroll
            for (int nt = 0; nt < 4; nt++) {
                float p = __expf(sv[nt][r] - mnew);
                pb[nt][r] = f2bf(p);
                s_ += p;
            }
#pragma unroll
            for (int off = 1; off < 16; off <<= 1) s_ += __shfl_xor(s_, off, 64);
            lrun[r] = lrun[r] * alpha[r] + s_;
            mrun[r] = mnew;
        }
#pragma unroll
        for (int nt = 0; nt < 4; nt++)
#pragma unroll
            for (int r = 0; r < 4; r++) oacc[nt][r] *= alpha[r];

        __syncthreads();   // previous iteration's Vt/Pw reads complete
        // P: C-layout -> LDS (A-layout readable)
#pragma unroll
        for (int nt = 0; nt < 4; nt++)
#pragma unroll
            for (int r = 0; r < 4; r++)
                Pw[w][(q4 * 4 + r) * 80 + nt * 16 + lm] = pb[nt][r];
        // stage V tile transposed: Vt[e][k] = V[k0+k][e]
        // FIX(R1): cover ALL 64 e-rows. 256 threads x 2 chunks x 8 elts = 4096
        // = full 64x64 tile (previous round staged only e 0..31 -> NaN from
        // uninitialized LDS propagated through the PV MFMA).
        {
            int k = t & 63;
#pragma unroll
            for (int cc = 0; cc < 2; ++cc) {
                int ech = (t >> 6) * 2 + cc;     // 0..7
                bf16x8 v8 = *(const bf16x8*)&Vb[(size_t)(k0 + k) * E_ + ech * 8];
#pragma unroll
                for (int j = 0; j < 8; j++)
                    Vt[(ech * 8 + j) * 80 + k] = (unsigned short)v8[j];
            }
        }
        __syncthreads();

        bf16x8 ap0 = *(const bf16x8*)&Pw[w][lm * 80 + q4 * 8];
        bf16x8 ap1 = *(const bf16x8*)&Pw[w][lm * 80 + 32 + q4 * 8];
#pragma unroll
        for (int nt = 0; nt < 4; nt++) {
            bf16x8 bv0 = *(const bf16x8*)&Vt[(nt * 16 + lm) * 80 + q4 * 8];
            bf16x8 bv1 = *(const bf16x8*)&Vt[(nt * 16 + lm) * 80 + 32 + q4 * 8];
            oacc[nt] = __builtin_amdgcn_mfma_f32_16x16x32_bf16(ap0, bv0, oacc[nt], 0, 0, 0);
            oacc[nt] = __builtin_amdgcn_mfma_f32_16x16x32_bf16(ap1, bv1, oacc[nt], 0, 0, 0);
        }
    }

    // normalize and write heads[b*S+s][h*64+e] (bf16, row-major for final GEMM)
#pragma unroll
    for (int nt = 0; nt < 4; nt++)
#pragma unroll
        for (int r = 0; r < 4; r++) {
            float o = oacc[nt][r] / lrun[r];
            int srow = qr0 + q4 * 4 + r;
            int col = h * E_ + nt * 16 + lm;
            heads[(size_t)(b * S_ + srow) * D_ + col] = f2bf(o);
        }
}

// ---------------------------------------------------------------------------
extern "C" void kernel_launch(void* const* d_in, const int* in_sizes, int n_in,
                              void* d_out, int out_size, void* d_ws, size_t ws_size,
                              hipStream_t stream) {
    char* ws = (char*)d_ws;
    int* flag = (int*)ws;
    unsigned short* WqT = (unsigned short*)(ws + 256);
    unsigned short* WkT = WqT + (size_t)D_ * D_;
    unsigned short* WvT = WkT + (size_t)D_ * D_;
    unsigned short* WoT = WvT + (size_t)D_ * D_;
    float* bq = (float*)(WoT + (size_t)D_ * D_);
    float* bk = bq + 1024;
    float* bv = bk + 1024;
    float* bo = bv + 1024;
    unsigned short* Qp = (unsigned short*)(bo + 1024);
    unsigned short* Kp = Qp + (size_t)B_ * H_ * S_ * E_;
    unsigned short* Vp = Kp + (size_t)B_ * H_ * S_ * E_;
    unsigned short* heads = Vp + (size_t)B_ * H_ * S_ * E_;
    // total ws use: ~40.2 MB

    detect_dtype<<<1, 256, 0, stream>>>((const unsigned int*)d_in[0], flag);
    conv_w<<<4096, 256, 0, stream>>>(d_in[4], d_in[6], d_in[8], d_in[10],
                                     d_in[5], d_in[7], d_in[9], d_in[11],
                                     WqT, WkT, WvT, WoT, bq, bk, bv, bo, flag);
    dim3 gg(D_ / 128, BS_ / 128);   // (8, 32)
    gemm128<<<gg, 256, 0, stream>>>(d_in[0], WqT, bq, Qp, 0, 0, flag);
    gemm128<<<gg, 256, 0, stream>>>(d_in[1], WkT, bk, Kp, 0, 0, flag);
    gemm128<<<gg, 256, 0, stream>>>(d_in[2], WvT, bv, Vp, 0, 0, flag);
    dim3 ga(S_ / 64, H_, B_);       // (16, 16, 4)
    attn64<<<ga, 256, 0, stream>>>(Qp, Kp, Vp, (const int*)d_in[3], heads);
    gemm128<<<gg, 256, 0, stream>>>(heads, WoT, bo, d_out, 1, 1, flag);
}

// Round 3
// 386.405 us; speedup vs baseline: 1.3149x; 1.3149x over previous
//
#include <hip/hip_runtime.h>

// Problem constants (B,S,D,H,HD) = (4,1024,1024,16,64)
#define B_ 4
#define S_ 1024
#define D_ 1024
#define H_ 16
#define E_ 64
#define BS_ (B_*S_)
#define BHSE_ (B_*H_*S_*E_)   // 4,194,304

typedef __attribute__((ext_vector_type(8))) short bf16x8;   // 8 bf16 in 4 VGPRs
typedef __attribute__((ext_vector_type(4))) float f32x4;

__device__ __forceinline__ unsigned short f2bf(float f) {
    unsigned int x = __float_as_uint(f);
    x = (x + 0x7FFFu + ((x >> 16) & 1u)) >> 16;   // RNE
    return (unsigned short)x;
}
__device__ __forceinline__ float bf2f(unsigned short u) {
    return __uint_as_float(((unsigned int)u) << 16);
}
__device__ __forceinline__ float ldin(const void* p, size_t i, int isb) {
    return isb ? bf2f(((const unsigned short*)p)[i]) : ((const float*)p)[i];
}

// async global->LDS, 16B per lane; LDS dest = wave-uniform base + lane*16
__device__ __forceinline__ void gl2lds16(const void* g, void* l) {
    __builtin_amdgcn_global_load_lds(
        (const __attribute__((address_space(1))) void*)g,
        (__attribute__((address_space(3))) void*)l, 16, 0, 0);
}

// ---------------------------------------------------------------------------
// Kernel 0: detect input dtype (1=bf16, 0=fp32) -- see R0 notes.
// ---------------------------------------------------------------------------
__global__ void detect_dtype(const unsigned int* q, int* flag) {
    __shared__ int cnt;
    if (threadIdx.x == 0) cnt = 0;
    __syncthreads();
    unsigned int w = q[threadIdx.x];
    unsigned int lo = w & 0xFFFFu;
    unsigned int e = (lo >> 7) & 0xFFu;
    int ok = (lo == 0u) || (e >= 100u && e <= 145u);
    atomicAdd(&cnt, ok);
    __syncthreads();
    if (threadIdx.x == 0) flag[0] = (cnt >= 240) ? 1 : 0;
}

// ---------------------------------------------------------------------------
// Kernel 1: weight permutes, WRITE-coalesced (R3: scattered reads hit L2;
// scattered 2B HBM writes were the slow direction).
//   WqT[(h*64+e)][d] = Wq[h][d][e]; WoT[o][d] = Wo[d][o]
// ---------------------------------------------------------------------------
__global__ void conv_w(const void* Wq, const void* Wk, const void* Wv, const void* Wo,
                       const void* bq_, const void* bk_, const void* bv_, const void* bo_,
                       unsigned short* WqT, unsigned short* WkT, unsigned short* WvT,
                       unsigned short* WoT,
                       float* bq, float* bk, float* bv, float* bo, const int* flag) {
    int isb = flag[0];
    int j = blockIdx.x * 256 + threadIdx.x;     // 0..1M-1
    {
        int d = j & 1023, he = j >> 10;         // he = h*64+e
        int h = he >> 6, e = he & 63;
        size_t src = (size_t)h * 65536 + (size_t)d * 64 + e;
        size_t dst = (size_t)he * D_ + d;       // consecutive lanes -> consecutive d
        WqT[dst] = f2bf(ldin(Wq, src, isb));
        WkT[dst] = f2bf(ldin(Wk, src, isb));
        WvT[dst] = f2bf(ldin(Wv, src, isb));
    }
    {
        int d = j & 1023, o = j >> 10;
        WoT[(size_t)o * D_ + d] = f2bf(ldin(Wo, (size_t)d * D_ + o, isb));
    }
    if (j < 1024) {
        bq[j] = ldin(bq_, j, isb);
        bk[j] = ldin(bk_, j, isb);
        bv[j] = ldin(bv_, j, isb);
        bo[j] = ldin(bo_, j, isb);
    }
}

// ---------------------------------------------------------------------------
// Kernel 2: mask bitpack, transposed: packT[b][kt][s] bit k = mask[b][s][kt*64+k]
// One wave per (b,s,kt): coalesced 256B read + __ballot -> one ulong.
// ---------------------------------------------------------------------------
__global__ void maskpack(const int* mask, unsigned long long* packT) {
    int W = blockIdx.x * 4 + (threadIdx.x >> 6);    // 0..65535
    int lane = threadIdx.x & 63;
    int b = W >> 14, rem = W & 16383, s = rem >> 4, kt = rem & 15;
    int mv = mask[((size_t)b * 1024 + s) * 1024 + kt * 64 + lane];
    unsigned long long bits = __ballot(mv != 0);
    if (lane == 0) packT[((size_t)b * 16 + kt) * 1024 + s] = bits;
}

// ---------------------------------------------------------------------------
// Kernel 3: bf16 MFMA GEMM, m97-style global_load_lds staging, unpadded LDS.
// C[M][N] = A[M][K] * Bt[N][K]^T + bias[N], K=1024, N-tile=128, M-tile=BM.
// MODE 0: 3 projections via blockIdx.z (z=0 Q->[b][h][s][e], z=1 K same,
//         z=2 V TRANSPOSED -> [b][h][e][s] so attention PV needs no LDS V).
// MODE 1: final GEMM (A=heads bf16), writes d_out per dtype flag.
// ---------------------------------------------------------------------------
template<int BM, int MODE>
__global__ __launch_bounds__(256) void gemm_k(
        const void* A0, const void* A1, const void* A2,
        const unsigned short* BtB, const float* biasB, void* dstB, const int* flag) {
    constexpr int TOT16 = (BM + 128) * 32;      // LDS ushorts: [A BMx32 | B 128x32]
    constexpr int CALLS = TOT16 / 512;          // 1KB (64 lanes x 16B) chunks
    constexpr int CPW = CALLS / 4;
    constexpr int MT = BM / 32;                 // m-frags per wave
    __shared__ unsigned short buf[TOT16];

    const int t = threadIdx.x, lane = t & 63, w = t >> 6;
    const int lm = lane & 15, q4 = lane >> 4;
    const int wm = w >> 1, wn = w & 1;
    const int fl = flag[0];

    const void* A; const unsigned short* Bt; const float* bias;
    int aisb, z = 0;
    if (MODE == 0) {
        z = blockIdx.z;
        A = (z == 0) ? A0 : (z == 1 ? A1 : A2);
        Bt = BtB + (size_t)z * D_ * D_;
        bias = biasB + z * 1024;
        aisb = fl;
    } else {
        A = A0; Bt = BtB; bias = biasB; aisb = 1;
    }
    const int m0 = blockIdx.y * BM, n0 = blockIdx.x * 128;

    f32x4 acc[MT][4];
#pragma unroll
    for (int i = 0; i < MT; i++)
#pragma unroll
        for (int j = 0; j < 4; j++) acc[i][j] = (f32x4){0.f, 0.f, 0.f, 0.f};

    for (int kk = 0; kk < D_; kk += 32) {
        __syncthreads();                          // prior frag reads done
        if (aisb) {
#pragma unroll
            for (int i = 0; i < CPW; ++i) {
                int call = w * CPW + i;
                int u = call * 512 + lane * 8;    // ushort idx in buf
                const unsigned short* g;
                if (u < BM * 32) {
                    int row = u >> 5, cc = u & 31;
                    g = (const unsigned short*)A + (size_t)(m0 + row) * D_ + kk + cc;
                } else {
                    int ub = u - BM * 32;
                    int row = ub >> 5, cc = ub & 31;
                    g = Bt + (size_t)(n0 + row) * D_ + kk + cc;
                }
                gl2lds16(g, buf + call * 512);
            }
        } else {
            // fp32 A path: convert via regs; B still async (always bf16)
#pragma unroll
            for (int i = 0; i < CPW; ++i) {
                int call = w * CPW + i;
                int u = call * 512 + lane * 8;
                if (u < BM * 32) {
                    int row = u >> 5, cc = u & 31;
                    const float* af = (const float*)A + (size_t)(m0 + row) * D_ + kk + cc;
                    bf16x8 v;
#pragma unroll
                    for (int jj = 0; jj < 8; jj++) v[jj] = (short)f2bf(af[jj]);
                    *(bf16x8*)(buf + u) = v;
                } else {
                    int ub = u - BM * 32;
                    int row = ub >> 5, cc = ub & 31;
                    gl2lds16(Bt + (size_t)(n0 + row) * D_ + kk + cc, buf + call * 512);
                }
            }
        }
        __syncthreads();                          // drains vmcnt+lgkmcnt

        const unsigned short* As = buf;
        const unsigned short* Bs = buf + BM * 32;
        bf16x8 af[MT], bv[4];
#pragma unroll
        for (int mt = 0; mt < MT; mt++)
            af[mt] = *(const bf16x8*)&As[(wm * (BM / 2) + mt * 16 + lm) * 32 + q4 * 8];
#pragma unroll
        for (int nt = 0; nt < 4; nt++)
            bv[nt] = *(const bf16x8*)&Bs[(wn * 64 + nt * 16 + lm) * 32 + q4 * 8];
#pragma unroll
        for (int mt = 0; mt < MT; mt++)
#pragma unroll
            for (int nt = 0; nt < 4; nt++)
                acc[mt][nt] = __builtin_amdgcn_mfma_f32_16x16x32_bf16(
                    af[mt], bv[nt], acc[mt][nt], 0, 0, 0);
    }

    // epilogue: C/D layout col=lane&15, row=(lane>>4)*4+reg
#pragma unroll
    for (int mt = 0; mt < MT; mt++)
#pragma unroll
        for (int nt = 0; nt < 4; nt++)
#pragma unroll
            for (int r = 0; r < 4; r++) {
                int M = m0 + wm * (BM / 2) + mt * 16 + q4 * 4 + r;
                int N = n0 + wn * 64 + nt * 16 + lm;
                float v = acc[mt][nt][r] + bias[N];
                if (MODE == 0) {
                    int bb = M >> 10, s = M & 1023, hh = N >> 6, e = N & 63;
                    unsigned short* d16 = (unsigned short*)dstB + (size_t)z * BHSE_;
                    if (z < 2)
                        d16[((size_t)(bb * H_ + hh) * S_ + s) * E_ + e] = f2bf(v);
                    else
                        d16[((size_t)(bb * H_ + hh) * E_ + e) * S_ + s] = f2bf(v);
                } else {
                    size_t idx = (size_t)M * D_ + N;
                    if (fl) ((unsigned short*)dstB)[idx] = f2bf(v);
                    else    ((float*)dstB)[idx] = v;
                }
            }
}

// ---------------------------------------------------------------------------
// Kernel 4: fused attention, transposed-score formulation. NO __syncthreads.
// Wave = 16 q-rows. Sc^T = K.Q^T (A=K rows, B=Q rows, both global-contig).
// Lane column = q => softmax state scalar/lane, 2 shuffles per reduction,
// mask = 1 packed ulong per lane per 64-key tile. out^T = V^T.P^T with V^T
// A-frags direct from global ([b][h][e][s] layout); P via per-wave LDS only.
// ---------------------------------------------------------------------------
__global__ __launch_bounds__(256) void attn64(
        const unsigned short* Qp, const unsigned short* Kp, const unsigned short* VpT,
        const unsigned long long* packT, unsigned short* heads) {
    __shared__ unsigned short Pw[4][16 * 72];   // per-wave P[q][k], stride 72

    const int qt = blockIdx.x, h = blockIdx.y, b = blockIdx.z;
    const int t = threadIdx.x, w = t >> 6, lane = t & 63, lm = lane & 15, q4 = lane >> 4;
    const size_t bh = ((size_t)b * H_ + h) * S_ * E_;   // == (b*H+h)*E*S
    const unsigned short* Qb = Qp + bh;
    const unsigned short* Kb = Kp + bh;
    const unsigned short* Vb = VpT + bh;                // Vb[e*1024 + s]
    const int q0 = qt * 64 + w * 16;
    unsigned short* P = &Pw[w][0];

    // Q B-fragments (B[k=e][n=q] = Q[q][e]): held for the whole sweep
    bf16x8 bq0 = *(const bf16x8*)&Qb[(size_t)(q0 + lm) * E_ + q4 * 8];
    bf16x8 bq1 = *(const bf16x8*)&Qb[(size_t)(q0 + lm) * E_ + 32 + q4 * 8];

    f32x4 oacc[4];
#pragma unroll
    for (int i = 0; i < 4; i++) oacc[i] = (f32x4){0.f, 0.f, 0.f, 0.f};
    float mrun = -3.0e38f, lrun = 0.f;
    const float scale = 0.03125f;   // 1/sqrt(D=1024), faithful to ref

    for (int kt = 0; kt < S_ / 64; ++kt) {
        const int k0 = kt * 64;
        unsigned long long mk = packT[((size_t)b * 16 + kt) * 1024 + q0 + lm];

        // Sc^T tiles: jt over 4 key-groups of 16; lane reg r -> key jt*16+q4*4+r, q=lm
        f32x4 st[4];
#pragma unroll
        for (int jt = 0; jt < 4; ++jt) {
            bf16x8 ka0 = *(const bf16x8*)&Kb[(size_t)(k0 + jt * 16 + lm) * E_ + q4 * 8];
            bf16x8 ka1 = *(const bf16x8*)&Kb[(size_t)(k0 + jt * 16 + lm) * E_ + 32 + q4 * 8];
            f32x4 zz = (f32x4){0.f, 0.f, 0.f, 0.f};
            zz = __builtin_amdgcn_mfma_f32_16x16x32_bf16(ka0, bq0, zz, 0, 0, 0);
            zz = __builtin_amdgcn_mfma_f32_16x16x32_bf16(ka1, bq1, zz, 0, 0, 0);
            st[jt] = zz;
        }
        float sv[4][4];
        float tmx = -3.0e38f;
#pragma unroll
        for (int jt = 0; jt < 4; ++jt)
#pragma unroll
            for (int r = 0; r < 4; r++) {
                int kb = jt * 16 + q4 * 4 + r;
                float x = ((mk >> kb) & 1ull) ? st[jt][r] * scale : -3.0e38f;
                sv[jt][r] = x;
                tmx = fmaxf(tmx, x);
            }
        // column-q reduction: lanes lm, lm+16, lm+32, lm+48
        tmx = fmaxf(tmx, __shfl_xor(tmx, 16, 64));
        tmx = fmaxf(tmx, __shfl_xor(tmx, 32, 64));
        float mnew = fmaxf(mrun, tmx);
        float alpha = __expf(mrun - mnew);   // fully-masked-so-far self-corrects
        float ssum = 0.f;
        unsigned long long pk[4];
#pragma unroll
        for (int jt = 0; jt < 4; ++jt) {
            float p0 = __expf(sv[jt][0] - mnew);
            float p1 = __expf(sv[jt][1] - mnew);
            float p2 = __expf(sv[jt][2] - mnew);
            float p3 = __expf(sv[jt][3] - mnew);
            ssum += (p0 + p1) + (p2 + p3);
            pk[jt] = (unsigned long long)f2bf(p0)
                   | ((unsigned long long)f2bf(p1) << 16)
                   | ((unsigned long long)f2bf(p2) << 32)
                   | ((unsigned long long)f2bf(p3) << 48);
        }
        ssum += __shfl_xor(ssum, 16, 64);
        ssum += __shfl_xor(ssum, 32, 64);
        lrun = lrun * alpha + ssum;
        mrun = mnew;
#pragma unroll
        for (int nt = 0; nt < 4; nt++) oacc[nt] = oacc[nt] * alpha;

        // P[q=lm][k] -> per-wave LDS (b64 writes, r-consecutive); same-wave
        // in-order DS pipe => no barrier needed before the b128 reads below.
#pragma unroll
        for (int jt = 0; jt < 4; ++jt)
            *(unsigned long long*)&P[lm * 72 + jt * 16 + q4 * 4] = pk[jt];

        bf16x8 bp0 = *(const bf16x8*)&P[lm * 72 + q4 * 8];        // k 0..31
        bf16x8 bp1 = *(const bf16x8*)&P[lm * 72 + 32 + q4 * 8];   // k 32..63
#pragma unroll
        for (int nt = 0; nt < 4; nt++) {
            bf16x8 va0 = *(const bf16x8*)&Vb[(size_t)(nt * 16 + lm) * S_ + k0 + q4 * 8];
            bf16x8 va1 = *(const bf16x8*)&Vb[(size_t)(nt * 16 + lm) * S_ + k0 + 32 + q4 * 8];
            oacc[nt] = __builtin_amdgcn_mfma_f32_16x16x32_bf16(va0, bp0, oacc[nt], 0, 0, 0);
            oacc[nt] = __builtin_amdgcn_mfma_f32_16x16x32_bf16(va1, bp1, oacc[nt], 0, 0, 0);
        }
    }

    // out^T C-layout: lane holds (e = nt*16+q4*4+r, q = lm); write b64 per nt
    float inv = 1.0f / lrun;
#pragma unroll
    for (int nt = 0; nt < 4; nt++) {
        unsigned long long hv =
              (unsigned long long)f2bf(oacc[nt][0] * inv)
            | ((unsigned long long)f2bf(oacc[nt][1] * inv) << 16)
            | ((unsigned long long)f2bf(oacc[nt][2] * inv) << 32)
            | ((unsigned long long)f2bf(oacc[nt][3] * inv) << 48);
        *(unsigned long long*)&heads[(size_t)(b * S_ + q0 + lm) * D_ + h * E_ + nt * 16 + q4 * 4] = hv;
    }
}

// ---------------------------------------------------------------------------
extern "C" void kernel_launch(void* const* d_in, const int* in_sizes, int n_in,
                              void* d_out, int out_size, void* d_ws, size_t ws_size,
                              hipStream_t stream) {
    char* ws = (char*)d_ws;
    int* flag = (int*)ws;
    unsigned short* WqT = (unsigned short*)(ws + 256);
    unsigned short* WkT = WqT + (size_t)D_ * D_;
    unsigned short* WvT = WkT + (size_t)D_ * D_;
    unsigned short* WoT = WvT + (size_t)D_ * D_;
    float* bq = (float*)(WoT + (size_t)D_ * D_);
    float* bk = bq + 1024;
    float* bv = bk + 1024;
    float* bo = bv + 1024;
    unsigned short* Qp = (unsigned short*)(bo + 1024);   // [b][h][s][e]
    unsigned short* Kp = Qp + (size_t)BHSE_;             // [b][h][s][e]
    unsigned short* Vp = Kp + (size_t)BHSE_;             // [b][h][e][s] (transposed)
    unsigned short* heads = Vp + (size_t)BHSE_;          // [b*s][h*64+e]
    unsigned long long* packT = (unsigned long long*)(heads + (size_t)BHSE_);  // +512KB

    detect_dtype<<<1, 256, 0, stream>>>((const unsigned int*)d_in[0], flag);
    conv_w<<<4096, 256, 0, stream>>>(d_in[4], d_in[6], d_in[8], d_in[10],
                                     d_in[5], d_in[7], d_in[9], d_in[11],
                                     WqT, WkT, WvT, WoT, bq, bk, bv, bo, flag);
    maskpack<<<16384, 256, 0, stream>>>((const int*)d_in[3], packT);
    gemm_k<128, 0><<<dim3(8, 32, 3), 256, 0, stream>>>(
        d_in[0], d_in[1], d_in[2], WqT, bq, Qp, flag);
    attn64<<<dim3(16, 16, 4), 256, 0, stream>>>(Qp, Kp, Vp, packT, heads);
    gemm_k<64, 1><<<dim3(8, 64, 1), 256, 0, stream>>>(
        heads, nullptr, nullptr, WoT, bo, d_out, flag);
}

// Round 4
// 312.891 us; speedup vs baseline: 1.6238x; 1.2350x over previous
//
#include <hip/hip_runtime.h>

// Problem constants (B,S,D,H,HD) = (4,1024,1024,16,64)
#define B_ 4
#define S_ 1024
#define D_ 1024
#define H_ 16
#define E_ 64
#define BS_ (B_*S_)
#define BHSE_ (B_*H_*S_*E_)   // 4,194,304

typedef __attribute__((ext_vector_type(8))) short bf16x8;   // 8 bf16 in 4 VGPRs
typedef __attribute__((ext_vector_type(4))) float f32x4;

__device__ __forceinline__ unsigned short f2bf(float f) {
    unsigned int x = __float_as_uint(f);
    x = (x + 0x7FFFu + ((x >> 16) & 1u)) >> 16;   // RNE
    return (unsigned short)x;
}
__device__ __forceinline__ float bf2f(unsigned short u) {
    return __uint_as_float(((unsigned int)u) << 16);
}
__device__ __forceinline__ float ldin(const void* p, size_t i, int isb) {
    return isb ? bf2f(((const unsigned short*)p)[i]) : ((const float*)p)[i];
}

// 2^x : v_exp_f32 is natively base-2
#if __has_builtin(__builtin_amdgcn_exp2f)
#define EXP2(x) __builtin_amdgcn_exp2f(x)
#else
#define EXP2(x) __expf((x) * 0.6931471805599453f)
#endif

// async global->LDS, 16B per lane; LDS dest = wave-uniform base + lane*16
__device__ __forceinline__ void gl2lds16(const void* g, void* l) {
    __builtin_amdgcn_global_load_lds(
        (const __attribute__((address_space(1))) void*)g,
        (__attribute__((address_space(3))) void*)l, 16, 0, 0);
}

// ---------------------------------------------------------------------------
// Kernel 0: detect input dtype (1=bf16, 0=fp32) -- see R0 notes.
// ---------------------------------------------------------------------------
__global__ void detect_dtype(const unsigned int* q, int* flag) {
    __shared__ int cnt;
    if (threadIdx.x == 0) cnt = 0;
    __syncthreads();
    unsigned int w = q[threadIdx.x];
    unsigned int lo = w & 0xFFFFu;
    unsigned int e = (lo >> 7) & 0xFFu;
    int ok = (lo == 0u) || (e >= 100u && e <= 145u);
    atomicAdd(&cnt, ok);
    __syncthreads();
    if (threadIdx.x == 0) flag[0] = (cnt >= 240) ? 1 : 0;
}

// ---------------------------------------------------------------------------
// Kernel 1 (R4): weight permutes via LDS-transposed 64x64 tiles -- BOTH global
// directions coalesced (R3's lane-strided reads had 32x line amplification).
// z=0..2: W{q,k,v}[h][d][e] -> WT[z][(h*64+e)][d]; z=3: Wo[d][o] -> WT[3][o][d].
// ---------------------------------------------------------------------------
__global__ __launch_bounds__(256) void conv_w2(
        const void* Wq, const void* Wk, const void* Wv, const void* Wo,
        const void* bq_, const void* bk_, const void* bv_, const void* bo_,
        unsigned short* WT, float* biases, const int* flag) {
    __shared__ unsigned short Tt[64][72];
    const int isb = flag[0];
    const int z = blockIdx.z, t = threadIdx.x;
    const void* src = (z == 0) ? Wq : (z == 1) ? Wk : (z == 2) ? Wv : Wo;
    const int r0 = blockIdx.y * 64;          // d-tile origin
    const int c0 = blockIdx.x;               // head (z<3) or o-tile (z=3)
    {
        int dl = t >> 2, qc = t & 3;
        size_t base;
        if (z < 3) base = (size_t)c0 * 65536 + (size_t)(r0 + dl) * 64 + qc * 16;
        else       base = (size_t)(r0 + dl) * 1024 + (size_t)c0 * 64 + qc * 16;
        if (isb) {
            const unsigned short* s = (const unsigned short*)src + base;
            bf16x8 a0 = *(const bf16x8*)s, a1 = *(const bf16x8*)(s + 8);
#pragma unroll
            for (int j = 0; j < 8; j++) {
                Tt[qc * 16 + j][dl] = (unsigned short)a0[j];
                Tt[qc * 16 + 8 + j][dl] = (unsigned short)a1[j];
            }
        } else {
            const float* s = (const float*)src + base;
#pragma unroll
            for (int j = 0; j < 16; j++) Tt[qc * 16 + j][dl] = f2bf(s[j]);
        }
    }
    __syncthreads();
    {
        int el = t >> 2, qc = t & 3;
        size_t dst = (size_t)z * D_ * D_ + (size_t)(c0 * 64 + el) * D_ + r0 + qc * 16;
        *(bf16x8*)&WT[dst]     = *(const bf16x8*)&Tt[el][qc * 16];
        *(bf16x8*)&WT[dst + 8] = *(const bf16x8*)&Tt[el][qc * 16 + 8];
    }
    if (z == 3 && blockIdx.y == 0 && blockIdx.x < 4) {
        const void* bs = (blockIdx.x == 0) ? bq_ : (blockIdx.x == 1) ? bk_
                       : (blockIdx.x == 2) ? bv_ : bo_;
#pragma unroll
        for (int j = 0; j < 4; j++) {
            int i = t * 4 + j;
            biases[blockIdx.x * 1024 + i] = ldin(bs, i, isb);
        }
    }
}

// ---------------------------------------------------------------------------
// Kernel 2: mask bitpack, transposed: packT[b][kt][s] bit k = mask[b][s][kt*64+k]
// ---------------------------------------------------------------------------
__global__ void maskpack(const int* mask, unsigned long long* packT) {
    int W = blockIdx.x * 4 + (threadIdx.x >> 6);    // 0..65535
    int lane = threadIdx.x & 63;
    int b = W >> 14, rem = W & 16383, s = rem >> 4, kt = rem & 15;
    int mv = mask[((size_t)b * 1024 + s) * 1024 + kt * 64 + lane];
    unsigned long long bits = __ballot(mv != 0);
    if (lane == 0) packT[((size_t)b * 16 + kt) * 1024 + s] = bits;
}

// ---------------------------------------------------------------------------
// Kernel 3: bf16 MFMA GEMM, m97-style global_load_lds staging, unpadded LDS.
// (unchanged from R3 -- awaiting its counters before touching)
// ---------------------------------------------------------------------------
template<int BM, int MODE>
__global__ __launch_bounds__(256) void gemm_k(
        const void* A0, const void* A1, const void* A2,
        const unsigned short* BtB, const float* biasB, void* dstB, const int* flag) {
    constexpr int TOT16 = (BM + 128) * 32;
    constexpr int CALLS = TOT16 / 512;
    constexpr int CPW = CALLS / 4;
    constexpr int MT = BM / 32;
    __shared__ unsigned short buf[TOT16];

    const int t = threadIdx.x, lane = t & 63, w = t >> 6;
    const int lm = lane & 15, q4 = lane >> 4;
    const int wm = w >> 1, wn = w & 1;
    const int fl = flag[0];

    const void* A; const unsigned short* Bt; const float* bias;
    int aisb, z = 0;
    if (MODE == 0) {
        z = blockIdx.z;
        A = (z == 0) ? A0 : (z == 1 ? A1 : A2);
        Bt = BtB + (size_t)z * D_ * D_;
        bias = biasB + z * 1024;
        aisb = fl;
    } else {
        A = A0; Bt = BtB; bias = biasB; aisb = 1;
    }
    const int m0 = blockIdx.y * BM, n0 = blockIdx.x * 128;

    f32x4 acc[MT][4];
#pragma unroll
    for (int i = 0; i < MT; i++)
#pragma unroll
        for (int j = 0; j < 4; j++) acc[i][j] = (f32x4){0.f, 0.f, 0.f, 0.f};

    for (int kk = 0; kk < D_; kk += 32) {
        __syncthreads();
        if (aisb) {
#pragma unroll
            for (int i = 0; i < CPW; ++i) {
                int call = w * CPW + i;
                int u = call * 512 + lane * 8;
                const unsigned short* g;
                if (u < BM * 32) {
                    int row = u >> 5, cc = u & 31;
                    g = (const unsigned short*)A + (size_t)(m0 + row) * D_ + kk + cc;
                } else {
                    int ub = u - BM * 32;
                    int row = ub >> 5, cc = ub & 31;
                    g = Bt + (size_t)(n0 + row) * D_ + kk + cc;
                }
                gl2lds16(g, buf + call * 512);
            }
        } else {
#pragma unroll
            for (int i = 0; i < CPW; ++i) {
                int call = w * CPW + i;
                int u = call * 512 + lane * 8;
                if (u < BM * 32) {
                    int row = u >> 5, cc = u & 31;
                    const float* af = (const float*)A + (size_t)(m0 + row) * D_ + kk + cc;
                    bf16x8 v;
#pragma unroll
                    for (int jj = 0; jj < 8; jj++) v[jj] = (short)f2bf(af[jj]);
                    *(bf16x8*)(buf + u) = v;
                } else {
                    int ub = u - BM * 32;
                    int row = ub >> 5, cc = ub & 31;
                    gl2lds16(Bt + (size_t)(n0 + row) * D_ + kk + cc, buf + call * 512);
                }
            }
        }
        __syncthreads();

        const unsigned short* As = buf;
        const unsigned short* Bs = buf + BM * 32;
        bf16x8 af[MT], bv[4];
#pragma unroll
        for (int mt = 0; mt < MT; mt++)
            af[mt] = *(const bf16x8*)&As[(wm * (BM / 2) + mt * 16 + lm) * 32 + q4 * 8];
#pragma unroll
        for (int nt = 0; nt < 4; nt++)
            bv[nt] = *(const bf16x8*)&Bs[(wn * 64 + nt * 16 + lm) * 32 + q4 * 8];
#pragma unroll
        for (int mt = 0; mt < MT; mt++)
#pragma unroll
            for (int nt = 0; nt < 4; nt++)
                acc[mt][nt] = __builtin_amdgcn_mfma_f32_16x16x32_bf16(
                    af[mt], bv[nt], acc[mt][nt], 0, 0, 0);
    }

#pragma unroll
    for (int mt = 0; mt < MT; mt++)
#pragma unroll
        for (int nt = 0; nt < 4; nt++)
#pragma unroll
            for (int r = 0; r < 4; r++) {
                int M = m0 + wm * (BM / 2) + mt * 16 + q4 * 4 + r;
                int N = n0 + wn * 64 + nt * 16 + lm;
                float v = acc[mt][nt][r] + bias[N];
                if (MODE == 0) {
                    int bb = M >> 10, s = M & 1023, hh = N >> 6, e = N & 63;
                    unsigned short* d16 = (unsigned short*)dstB + (size_t)z * BHSE_;
                    if (z < 2)
                        d16[((size_t)(bb * H_ + hh) * S_ + s) * E_ + e] = f2bf(v);
                    else
                        d16[((size_t)(bb * H_ + hh) * E_ + e) * S_ + s] = f2bf(v);
                } else {
                    size_t idx = (size_t)M * D_ + N;
                    if (fl) ((unsigned short*)dstB)[idx] = f2bf(v);
                    else    ((float*)dstB)[idx] = v;
                }
            }
}

// ---------------------------------------------------------------------------
// Kernel 4 (R4): fused attention with LDS-staged, double-buffered K/V tiles.
// Each 64-key tile fetched ONCE per block by global_load_lds DMA (contiguous,
// 16 x 1KB chunks), prefetched one iteration ahead; fragments read from LDS.
// 16B-granule XOR swizzle (cc ^= row&7) makes column b128 reads evenly spread
// (8 lanes/granule = LDS structural optimum) despite the DMA-forced unpadded
// layout. Softmax in base-2 domain. P round-trip stride 88 (S4=12 mod 32).
// ---------------------------------------------------------------------------
#define PSTR 88
__global__ __launch_bounds__(256) void attn64(
        const unsigned short* Qp, const unsigned short* Kp, const unsigned short* VpT,
        const unsigned long long* packT, unsigned short* heads) {
    __shared__ unsigned short KT[2][4096];   // [buf][64 keys x 64 e], swizzled
    __shared__ unsigned short VT[2][4096];   // [buf][64 e x 64 keys], swizzled
    __shared__ unsigned short Pw[4][16 * PSTR];

    const int qt = blockIdx.x, h = blockIdx.y, b = blockIdx.z;
    const int t = threadIdx.x, w = t >> 6, lane = t & 63, lm = lane & 15, q4 = lane >> 4;
    const size_t bh = ((size_t)b * H_ + h) * S_ * E_;
    const unsigned short* Qb = Qp + bh;
    const unsigned short* Kb = Kp + bh;
    const unsigned short* Vb = VpT + bh;                // Vb[e*1024 + s]
    const int q0 = qt * 64 + w * 16;
    unsigned short* P = &Pw[w][0];

    // per-lane invariant DMA source offsets (ushort units)
    const int l3 = lane >> 3, l7 = lane & 7;
    const int kLaneOff = l3 * 64 + (l7 ^ l3) * 8;       // within an 8-row K chunk
    const int vLaneOff = l3 * 1024 + (l7 ^ l3) * 8;     // within an 8-row V chunk

    // swizzled LDS fragment chunk indices (granule = 8 ushorts)
    const int sw = lm & 7;
    const int c0 = (q4 ^ sw) * 8, c1 = ((q4 ^ 4) ^ sw) * 8;

    // Q B-fragments, held for the whole sweep
    bf16x8 bq0 = *(const bf16x8*)&Qb[(size_t)(q0 + lm) * E_ + q4 * 8];
    bf16x8 bq1 = *(const bf16x8*)&Qb[(size_t)(q0 + lm) * E_ + 32 + q4 * 8];

    f32x4 oacc[4];
#pragma unroll
    for (int i = 0; i < 4; i++) oacc[i] = (f32x4){0.f, 0.f, 0.f, 0.f};
    float mrun = -3.0e38f, lrun = 0.f;
    const float scale2 = 0.03125f * 1.4426950408889634f;   // log2e / sqrt(D)

    // stage tile kt into buffer bufi: wave w issues chunks w*4 .. w*4+3
#define STAGE(ktile, bufi)                                                    \
    {                                                                         \
        int k0s = (ktile) * 64;                                               \
        _Pragma("unroll")                                                     \
        for (int i_ = 0; i_ < 4; ++i_) {                                      \
            int c_ = w * 4 + i_;                                              \
            if (c_ < 8) {                                                     \
                gl2lds16(Kb + (size_t)k0s * 64 + c_ * 512 + kLaneOff,         \
                         &KT[bufi][c_ * 512]);                                \
            } else {                                                          \
                int cc_ = c_ - 8;                                             \
                gl2lds16(Vb + (size_t)cc_ * 8192 + k0s + vLaneOff,            \
                         &VT[bufi][cc_ * 512]);                               \
            }                                                                 \
        }                                                                     \
    }

    STAGE(0, 0)

    for (int kt = 0; kt < S_ / 64; ++kt) {
        const int bufi = kt & 1;
        __syncthreads();                 // own-vmcnt drain + barrier: tile kt ready
        if (kt < 15) STAGE(kt + 1, bufi ^ 1)

        unsigned long long mk = packT[((size_t)b * 16 + kt) * 1024 + q0 + lm];

        // Sc^T from LDS K tile
        f32x4 st[4];
#pragma unroll
        for (int jt = 0; jt < 4; ++jt) {
            const unsigned short* kr = &KT[bufi][(jt * 16 + lm) * 64];
            bf16x8 ka0 = *(const bf16x8*)&kr[c0];
            bf16x8 ka1 = *(const bf16x8*)&kr[c1];
            f32x4 zz = (f32x4){0.f, 0.f, 0.f, 0.f};
            zz = __builtin_amdgcn_mfma_f32_16x16x32_bf16(ka0, bq0, zz, 0, 0, 0);
            zz = __builtin_amdgcn_mfma_f32_16x16x32_bf16(ka1, bq1, zz, 0, 0, 0);
            st[jt] = zz;
        }
        float sv[4][4];
        float tmx = -3.0e38f;
#pragma unroll
        for (int jt = 0; jt < 4; ++jt)
#pragma unroll
            for (int r = 0; r < 4; r++) {
                int kb = jt * 16 + q4 * 4 + r;
                float x = ((mk >> kb) & 1ull) ? st[jt][r] * scale2 : -3.0e38f;
                sv[jt][r] = x;
                tmx = fmaxf(tmx, x);
            }
        tmx = fmaxf(tmx, __shfl_xor(tmx, 16, 64));
        tmx = fmaxf(tmx, __shfl_xor(tmx, 32, 64));
        float mnew = fmaxf(mrun, tmx);
        float alpha = EXP2(mrun - mnew);
        float ssum = 0.f;
        unsigned long long pk[4];
#pragma unroll
        for (int jt = 0; jt < 4; ++jt) {
            float p0 = EXP2(sv[jt][0] - mnew);
            float p1 = EXP2(sv[jt][1] - mnew);
            float p2 = EXP2(sv[jt][2] - mnew);
            float p3 = EXP2(sv[jt][3] - mnew);
            ssum += (p0 + p1) + (p2 + p3);
            pk[jt] = (unsigned long long)f2bf(p0)
                   | ((unsigned long long)f2bf(p1) << 16)
                   | ((unsigned long long)f2bf(p2) << 32)
                   | ((unsigned long long)f2bf(p3) << 48);
        }
        ssum += __shfl_xor(ssum, 16, 64);
        ssum += __shfl_xor(ssum, 32, 64);
        lrun = lrun * alpha + ssum;
        mrun = mnew;
#pragma unroll
        for (int nt = 0; nt < 4; nt++) oacc[nt] = oacc[nt] * alpha;

        // P C->B layout via per-wave LDS (in-order DS pipe, no barrier)
#pragma unroll
        for (int jt = 0; jt < 4; ++jt)
            *(unsigned long long*)&P[lm * PSTR + jt * 16 + q4 * 4] = pk[jt];
        bf16x8 bp0 = *(const bf16x8*)&P[lm * PSTR + q4 * 8];
        bf16x8 bp1 = *(const bf16x8*)&P[lm * PSTR + 32 + q4 * 8];

        // PV from LDS V tile
#pragma unroll
        for (int nt = 0; nt < 4; nt++) {
            const unsigned short* vr = &VT[bufi][(nt * 16 + lm) * 64];
            bf16x8 va0 = *(const bf16x8*)&vr[c0];
            bf16x8 va1 = *(const bf16x8*)&vr[c1];
            oacc[nt] = __builtin_amdgcn_mfma_f32_16x16x32_bf16(va0, bp0, oacc[nt], 0, 0, 0);
            oacc[nt] = __builtin_amdgcn_mfma_f32_16x16x32_bf16(va1, bp1, oacc[nt], 0, 0, 0);
        }
    }

    float inv = 1.0f / lrun;
#pragma unroll
    for (int nt = 0; nt < 4; nt++) {
        unsigned long long hv =
              (unsigned long long)f2bf(oacc[nt][0] * inv)
            | ((unsigned long long)f2bf(oacc[nt][1] * inv) << 16)
            | ((unsigned long long)f2bf(oacc[nt][2] * inv) << 32)
            | ((unsigned long long)f2bf(oacc[nt][3] * inv) << 48);
        *(unsigned long long*)&heads[(size_t)(b * S_ + q0 + lm) * D_ + h * E_ + nt * 16 + q4 * 4] = hv;
    }
}

// ---------------------------------------------------------------------------
extern "C" void kernel_launch(void* const* d_in, const int* in_sizes, int n_in,
                              void* d_out, int out_size, void* d_ws, size_t ws_size,
                              hipStream_t stream) {
    char* ws = (char*)d_ws;
    int* flag = (int*)ws;
    unsigned short* WT = (unsigned short*)(ws + 256);    // [4][1024][1024] bf16
    unsigned short* WqT = WT;
    unsigned short* WoT = WT + (size_t)3 * D_ * D_;
    float* biases = (float*)(WT + (size_t)4 * D_ * D_);  // [4][1024]
    float* bq = biases;
    float* bo = biases + 3 * 1024;
    unsigned short* Qp = (unsigned short*)(biases + 4 * 1024);  // [b][h][s][e]
    unsigned short* Kp = Qp + (size_t)BHSE_;                    // [b][h][s][e]
    unsigned short* Vp = Kp + (size_t)BHSE_;                    // [b][h][e][s]
    unsigned short* heads = Vp + (size_t)BHSE_;                 // [b*s][h*64+e]
    unsigned long long* packT = (unsigned long long*)(heads + (size_t)BHSE_);

    detect_dtype<<<1, 256, 0, stream>>>((const unsigned int*)d_in[0], flag);
    conv_w2<<<dim3(16, 16, 4), 256, 0, stream>>>(
        d_in[4], d_in[6], d_in[8], d_in[10],
        d_in[5], d_in[7], d_in[9], d_in[11], WT, biases, flag);
    maskpack<<<16384, 256, 0, stream>>>((const int*)d_in[3], packT);
    gemm_k<128, 0><<<dim3(8, 32, 3), 256, 0, stream>>>(
        d_in[0], d_in[1], d_in[2], WqT, bq, Qp, flag);
    attn64<<<dim3(16, 16, 4), 256, 0, stream>>>(Qp, Kp, Vp, packT, heads);
    gemm_k<64, 1><<<dim3(8, 64, 1), 256, 0, stream>>>(
        heads, nullptr, nullptr, WoT, bo, d_out, flag);
}